// Round 15
// baseline (836.741 us; speedup 1.0000x reference)
//
#include <hip/hip_runtime.h>

#define NN 20000      // nodes
#define NNP 20096     // nodes padded to 128 (GEMM tiles, no M-checks)
#define NE 320000     // edges
#define NB 128        // graphs
// EMB = 256 fixed throughout

typedef __attribute__((ext_vector_type(8))) short short8;
typedef __attribute__((ext_vector_type(4))) float floatx4;
typedef __attribute__((ext_vector_type(2))) float floatv2;

__device__ __forceinline__ void atomAddF(float* p, float v) { unsafeAtomicAdd(p, v); }

__device__ __forceinline__ ushort f2bf(float x) {
    union { float f; unsigned u; } v; v.f = x;
    unsigned r = v.u + 0x7FFFu + ((v.u >> 16) & 1u);
    return (ushort)(r >> 16);
}
__device__ __forceinline__ float bf2f(ushort h) {
    union { float f; unsigned u; } v; v.u = ((unsigned)h) << 16;
    return v.f;
}

// ---------------------------------------------------------------------------
// Edge prep: degree histogram; rank[idx]; rbf4[idx] = {r0,r1,r2,0} (edge-indexed,
// coalesced). RBF truncated to 3 components (r3..r9 <= ~8e-13).
__global__ void k_edge_prep(const int* __restrict__ ai, const float* __restrict__ e,
                            int* __restrict__ deg, int* __restrict__ rankA,
                            float4* __restrict__ rbf4) {
    int idx = blockIdx.x * 256 + threadIdx.x;
    if (idx >= NE) return;
    rankA[idx] = atomicAdd(&deg[ai[2 * idx + 1]], 1);
    float w = e[idx * 4 + 3];
    float d0 = w;
    float d1 = w - (8.0f / 9.0f);
    float d2 = w - (16.0f / 9.0f);
    rbf4[idx] = make_float4(__expf(-10.0f * d0 * d0), __expf(-10.0f * d1 * d1),
                            __expf(-10.0f * d2 * d2), 0.0f);
}

// ---------------------------------------------------------------------------
// Node prep: x_s (bf16 hi/lo) = element_emb[x], x_v = ones, t0 = ttab[x]
__global__ void k_node_prep(const int* __restrict__ x, const float* __restrict__ element_emb,
                            const ushort* __restrict__ ttab, ushort* __restrict__ xsh,
                            ushort* __restrict__ xsl, float* __restrict__ xv_init,
                            ushort* __restrict__ t_bf) {
    int n = blockIdx.x, tid = threadIdx.x;
    int xe = x[n];
    float v = element_emb[xe * 256 + tid];
    ushort h = f2bf(v);
    xsh[n * 256 + tid] = h;
    xsl[n * 256 + tid] = f2bf(v - bf2f(h));
    t_bf[n * 256 + tid] = ttab[xe * 256 + tid];
    if (tid < 12) xv_init[n * 12 + tid] = 1.0f;
}

// ---------------------------------------------------------------------------
// Exclusive prefix sum of deg -> off, degree histogram + descending offsets,
// AND graph ranges from sorted gid. One block, 1024 threads.
__global__ void k_scan(const int* __restrict__ deg, const int* __restrict__ gid,
                       int* __restrict__ off, int* __restrict__ dofs,
                       int* __restrict__ grange) {
    __shared__ int ps[1024];
    __shared__ int dh[256];
    int tid = threadIdx.x;
    if (tid < 256) dh[tid] = 0;
    __syncthreads();
    int base = tid * 20;  // 1024*20 = 20480 >= NN
    int dl[20];
    int sum = 0;
#pragma unroll
    for (int i = 0; i < 20; i++) {
        int idx = base + i;
        dl[i] = (idx < NN) ? deg[idx] : 0;
        sum += dl[i];
    }
    ps[tid] = sum;
#pragma unroll
    for (int i = 0; i < 20; i++) {
        int idx = base + i;
        if (idx < NN) atomicAdd(&dh[min(dl[i], 255)], 1);
    }
    __syncthreads();
#pragma unroll
    for (int d = 1; d < 1024; d <<= 1) {
        int t = (tid >= d) ? ps[tid - d] : 0;
        __syncthreads();
        ps[tid] += t;
        __syncthreads();
    }
    int run = (tid > 0) ? ps[tid - 1] : 0;
#pragma unroll
    for (int i = 0; i < 20; i++) {
        int idx = base + i;
        if (idx < NN) {
            off[idx] = run;
            run += dl[i];
        }
    }
    if (tid == 1023) off[NN] = run;
    if (tid < 256) {
        int s = 0;
        for (int dd = tid + 1; dd < 256; dd++) s += dh[dd];
        dofs[tid] = s;
    }
    // graph ranges (independent of scan results)
#pragma unroll
    for (int i = 0; i < 20; i++) {
        int idx = base + i;
        if (idx < NN) {
            int g = gid[idx];
            int gp = (idx == 0) ? -1 : gid[idx - 1];
            for (int bb = gp + 1; bb <= g; bb++) grange[bb] = idx;
            if (idx == NN - 1)
                for (int bb = g + 1; bb <= NB; bb++) grange[bb] = NN;
        }
    }
}

// perm[pos] = node, pos grouped by degree descending (uniform-deg blocks).
__global__ void k_permute(const int* __restrict__ deg, const int* __restrict__ dofs,
                          int* __restrict__ dcur, int* __restrict__ perm) {
    int n = blockIdx.x * 256 + threadIdx.x;
    if (n >= NN) return;
    int d = min(deg[n], 255);
    int pos = dofs[d] + atomicAdd(&dcur[d], 1);
    perm[pos] = n;
}

// ---------------------------------------------------------------------------
// Scatter into CSR slots — NO atomics (rank precomputed), 8B per edge.
__global__ void k_scatter(const int* __restrict__ ai, const int* __restrict__ rankA,
                          const int* __restrict__ off, int2* __restrict__ se) {
    int idx = blockIdx.x * 256 + threadIdx.x;
    if (idx < 64) se[NE + idx] = make_int2(0, 0);  // zero pad for prefetch
    if (idx >= NE) return;
    int src = ai[2 * idx + 0], tgt = ai[2 * idx + 1];
    int p = off[tgt] + rankA[idx];
    se[p] = make_int2(src, idx);
}

// ---------------------------------------------------------------------------
// Merged weight prep (one dispatch, 228 blocks):
//  b in [0,84)    : ttab[el] = element_emb[el] @ Wm0_top -> bf16
//  b in [84,100)  : Wcomb/cc (idx = b-84: k = idx&3, j = idx>>2)
//  b in [100,228) : weight transpose + hi/lo split
__global__ void k_wprep_all(const float* __restrict__ element_emb,
                            const float* __restrict__ W_e, const float* __restrict__ b_e,
                            const float* __restrict__ Wm0, const float* __restrict__ Wm1,
                            const float* __restrict__ Wm2, const float* __restrict__ Wm3,
                            const float* __restrict__ bm0, const float* __restrict__ bm1,
                            const float* __restrict__ bm2, const float* __restrict__ bm3,
                            const float* __restrict__ Wu0, const float* __restrict__ Wu1,
                            const float* __restrict__ Wu2, const float* __restrict__ Wu3,
                            ushort* __restrict__ ttab, float* __restrict__ Wcomb,
                            float* __restrict__ cc, ushort* __restrict__ WT) {
    int b = blockIdx.x;
    int ch = threadIdx.x;
    if (b < 84) {
        float s = 0.0f;
        for (int r = 0; r < 256; r++)
            s = fmaf(element_emb[b * 256 + r], Wm0[r * 256 + ch], s);
        ttab[b * 256 + ch] = f2bf(s);
        return;
    }
    if (b < 100) {
        int idx = b - 84;
        int k = idx & 3, j = idx >> 2;
        const float* Wm = (j == 0) ? Wm0 : (j == 1) ? Wm1 : (j == 2) ? Wm2 : Wm3;
        const float* bm = (j == 0) ? bm0 : (j == 1) ? bm1 : (j == 2) ? bm2 : bm3;
        if (k < 3) {
            float s = 0.0f;
            for (int r = 0; r < 256; r++)
                s = fmaf(W_e[k * 256 + r], Wm[(256 + r) * 256 + ch], s);
            Wcomb[j * 768 + k * 256 + ch] = s;
        } else {
            float s = bm[ch];
            for (int r = 0; r < 256; r++)
                s = fmaf(b_e[r], Wm[(256 + r) * 256 + ch], s);
            cc[j * 256 + ch] = s;
        }
        return;
    }
    // transpose + split
    int idx = b - 100;
    int ktb = idx & 3, ntb = (idx >> 2) & 3, z = idx >> 4;
    const float* Ws[8] = {Wm0, Wu0, Wm1, Wu1, Wm2, Wu2, Wm3, Wu3};
    const float* W = Ws[z];
    ushort* outh = WT + (size_t)z * 131072;
    ushort* outl = outh + 65536;
    __shared__ float tile[64][65];
    int kt = ktb * 64, nt = ntb * 64;
    int c = ch & 63, rq = ch >> 6;
#pragma unroll
    for (int r0 = 0; r0 < 16; r0++) {
        int k = kt + rq * 16 + r0;
        tile[rq * 16 + r0][c] = W[k * 256 + nt + c];
    }
    __syncthreads();
#pragma unroll
    for (int r0 = 0; r0 < 16; r0++) {
        int n = nt + rq * 16 + r0;
        float v = tile[c][rq * 16 + r0];  // = W[kt+c][n]
        ushort h = f2bf(v);
        outh[n * 256 + kt + c] = h;
        outl[n * 256 + kt + c] = f2bf(v - bf2f(h));
    }
}

// ---------------------------------------------------------------------------
// bf16 hi/lo split-precision MFMA GEMM: C[NNP,256] = A[NNP,256] @ W[256,256].
// R9 structure (128x128 tile). Staging via global_load_lds width=16.
// Al==null -> skip AlBh; Bl==null -> skip AhBl.
__global__ __launch_bounds__(256) void k_gemm_bf16(
    const ushort* __restrict__ Ah, const ushort* __restrict__ Al,
    const ushort* __restrict__ Bh, const ushort* __restrict__ Bl,
    const float* __restrict__ bias,
    const ushort* __restrict__ Rh, const ushort* __restrict__ Rl,
    ushort* __restrict__ Coh, ushort* __restrict__ Col) {
    __shared__ __align__(16) ushort As[2][128][32];
    __shared__ __align__(16) ushort Bs[2][128][32];
    const int tid = threadIdx.x;
    const int lane = tid & 63, wid = tid >> 6;
    const int bm0 = blockIdx.x * 128, bn0 = blockIdx.y * 128;
    const int wm0 = (wid & 1) * 64, wn0 = (wid >> 1) * 64;
    const int lm = lane & 15, q8 = (lane >> 4) * 8;
    const int lr = lane >> 2, lp = lane & 3;  // 16-row group: row-in-group, 16B part
    floatx4 acc[4][4] = {};
    for (int k0 = 0; k0 < 256; k0 += 32) {
        __syncthreads();
        // async global->LDS: one instr = 64 lanes x 16B = 16 rows of a plane
#pragma unroll
        for (int q = 0; q < 2; q++) {
            int rw = (wid * 2 + q) * 16;
            int grow = rw + lr;
            size_t ga = (size_t)(bm0 + grow) * 256 + k0 + lp * 8;
            size_t gb = (size_t)(bn0 + grow) * 256 + k0 + lp * 8;
            __builtin_amdgcn_global_load_lds(
                (const __attribute__((address_space(1))) void*)(Ah + ga),
                (__attribute__((address_space(3))) void*)&As[0][rw][0], 16, 0, 0);
            if (Al)
                __builtin_amdgcn_global_load_lds(
                    (const __attribute__((address_space(1))) void*)(Al + ga),
                    (__attribute__((address_space(3))) void*)&As[1][rw][0], 16, 0, 0);
            __builtin_amdgcn_global_load_lds(
                (const __attribute__((address_space(1))) void*)(Bh + gb),
                (__attribute__((address_space(3))) void*)&Bs[0][rw][0], 16, 0, 0);
            if (Bl)
                __builtin_amdgcn_global_load_lds(
                    (const __attribute__((address_space(1))) void*)(Bl + gb),
                    (__attribute__((address_space(3))) void*)&Bs[1][rw][0], 16, 0, 0);
        }
        __syncthreads();
        short8 ah[4], al[4], bh[4], bl[4];
#pragma unroll
        for (int mt = 0; mt < 4; mt++) {
            ah[mt] = *(const short8*)&As[0][wm0 + mt * 16 + lm][q8];
            if (Al) al[mt] = *(const short8*)&As[1][wm0 + mt * 16 + lm][q8];
        }
#pragma unroll
        for (int nt = 0; nt < 4; nt++) {
            bh[nt] = *(const short8*)&Bs[0][wn0 + nt * 16 + lm][q8];
            if (Bl) bl[nt] = *(const short8*)&Bs[1][wn0 + nt * 16 + lm][q8];
        }
#pragma unroll
        for (int mt = 0; mt < 4; mt++)
#pragma unroll
            for (int nt = 0; nt < 4; nt++) {
                acc[mt][nt] = __builtin_amdgcn_mfma_f32_16x16x32_bf16(ah[mt], bh[nt], acc[mt][nt], 0, 0, 0);
                if (Al)
                    acc[mt][nt] = __builtin_amdgcn_mfma_f32_16x16x32_bf16(al[mt], bh[nt], acc[mt][nt], 0, 0, 0);
                if (Bl)
                    acc[mt][nt] = __builtin_amdgcn_mfma_f32_16x16x32_bf16(ah[mt], bl[nt], acc[mt][nt], 0, 0, 0);
            }
    }
    const int rq4 = (lane >> 4) * 4;
#pragma unroll
    for (int mt = 0; mt < 4; mt++) {
        int rbase = bm0 + wm0 + mt * 16 + rq4;
#pragma unroll
        for (int nt = 0; nt < 4; nt++) {
            int col = bn0 + wn0 + nt * 16 + lm;
#pragma unroll
            for (int r = 0; r < 4; r++) {
                int row = rbase + r;
                float v = acc[mt][nt][r];
                if (!Col) {
                    Coh[row * 256 + col] = f2bf(v);
                } else {
                    v += bias[col];
                    v = fmaxf(v, 0.0f);
                    if (Rh) v += bf2f(Rh[row * 256 + col]) + bf2f(Rl[row * 256 + col]);
                    ushort h = f2bf(v);
                    Coh[row * 256 + col] = h;
                    Col[row * 256 + col] = f2bf(v - bf2f(h));
                }
            }
        }
    }
}

// ---------------------------------------------------------------------------
// Fused edge kernel: one wave per node (degree-sorted via perm), 4 ch/lane,
// unrolled x2. R15: T outer-product + Tb/Te accumulation in packed fp32
// (v_pk_fma_f32 / v_pk_add_f32, VOP3P): 48 fma -> 24 pk_fma, 12 add -> 6
// pk_add per edge (~30% issue cut; R14 showed k_edge mixed issue/latency).
// T layout (j = d*4+c): [Xa.x,Xa.y,Xa.z,E.x | Xa.w,Xb.x,Xb.y,E.y | Xb.z,Xb.w,Xc,E.z]
// packed as 6 floatv2 per channel; TbF (unweighted basis sum) same layout.
__global__ __launch_bounds__(256) void k_edge(const int* __restrict__ perm,
                                              const int2* __restrict__ seP,
                                              const int* __restrict__ off,
                                              const ushort* __restrict__ tbf,
                                              const float* __restrict__ xv_old,
                                              const float4* __restrict__ e4,
                                              const float4* __restrict__ rbf4,
                                              const float* __restrict__ Wcomb,
                                              const float* __restrict__ cc,
                                              const float* __restrict__ Wg,
                                              const float* __restrict__ bg,
                                              ushort* __restrict__ sah,
                                              ushort* __restrict__ sal,
                                              float* __restrict__ x_e,
                                              float* __restrict__ xv_new, int addResid) {
    const int lane = threadIdx.x & 63, wid = threadIdx.x >> 6;
    const int n = perm[blockIdx.x * 4 + wid];
    const int chb = lane * 4;  // this lane's 4 channels
    const int start = off[n];
    const int deg = off[n + 1] - start;
    float wcs0[4], wcs1[4], wcs2[4], ccs[4];
    {
        float4 a = *(const float4*)(Wcomb + chb);
        float4 b = *(const float4*)(Wcomb + 256 + chb);
        float4 c = *(const float4*)(Wcomb + 512 + chb);
        float4 d = *(const float4*)(cc + chb);
        wcs0[0] = a.x; wcs0[1] = a.y; wcs0[2] = a.z; wcs0[3] = a.w;
        wcs1[0] = b.x; wcs1[1] = b.y; wcs1[2] = b.z; wcs1[3] = b.w;
        wcs2[0] = c.x; wcs2[1] = c.y; wcs2[2] = c.z; wcs2[3] = c.w;
        ccs[0] = d.x; ccs[1] = d.y; ccs[2] = d.z; ccs[3] = d.w;
    }
    floatv2 T2[4][6] = {};
    floatv2 Tb2[6] = {};
    float ss[4] = {};
    const float4* xv4 = (const float4*)xv_old;

    auto edge = [&](ushort4 t, float4 E, float4 R, float4 Xa, float4 Xb, float Xc) {
        floatv2 B2[6];
        B2[0] = floatv2{Xa.x, Xa.y};
        B2[1] = floatv2{Xa.z, E.x};
        B2[2] = floatv2{Xa.w, Xb.x};
        B2[3] = floatv2{Xb.y, E.y};
        B2[4] = floatv2{Xb.z, Xb.w};
        B2[5] = floatv2{Xc, E.z};
        float tf[4] = {bf2f(t.x), bf2f(t.y), bf2f(t.z), bf2f(t.w)};
#pragma unroll
        for (int c = 0; c < 4; c++) {
            float m = tf[c] + ccs[c];
            m = fmaf(R.x, wcs0[c], m);
            m = fmaf(R.y, wcs1[c], m);
            m = fmaf(R.z, wcs2[c], m);
            m = fmaxf(m, 0.0f);
            ss[c] += m;
            floatv2 mm = floatv2{m, m};
#pragma unroll
            for (int p = 0; p < 6; p++)
                asm("v_pk_fma_f32 %0, %1, %2, %0" : "+v"(T2[c][p]) : "v"(B2[p]), "v"(mm));
        }
#pragma unroll
        for (int p = 0; p < 6; p++)
            asm("v_pk_add_f32 %0, %1, %0" : "+v"(Tb2[p]) : "v"(B2[p]));
    };

    if (deg > 0) {
        int2 q0 = seP[start + 0], q1 = seP[start + 1], q2 = seP[start + 2],
             q3 = seP[start + 3], q4 = seP[start + 4], q5 = seP[start + 5];
        ushort4 t0 = *(const ushort4*)(tbf + (size_t)q0.x * 256 + chb);
        ushort4 t1 = *(const ushort4*)(tbf + (size_t)q1.x * 256 + chb);
        ushort4 t2 = *(const ushort4*)(tbf + (size_t)q2.x * 256 + chb);
        ushort4 t3 = *(const ushort4*)(tbf + (size_t)q3.x * 256 + chb);
        float4 EA = e4[q0.y], RA = rbf4[q0.y];
        float4 EB = e4[q1.y], RB = rbf4[q1.y];
        float4 XaA = xv4[q0.x * 3 + 0], XbA = xv4[q0.x * 3 + 1];
        float XcA = xv_old[q0.x * 12 + 8];
        float4 XaB = xv4[q1.x * 3 + 0], XbB = xv4[q1.x * 3 + 1];
        float XcB = xv_old[q1.x * 12 + 8];
        int i = 0;
        for (; i + 1 < deg; i += 2) {
            // prefetch (all chain-free: induction addresses or >=2-iter-old regs)
            int2 q6 = seP[start + i + 6];
            int2 q7 = seP[start + i + 7];
            ushort4 t4 = *(const ushort4*)(tbf + (size_t)q4.x * 256 + chb);
            ushort4 t5 = *(const ushort4*)(tbf + (size_t)q5.x * 256 + chb);
            float4 EC = e4[q2.y], RC = rbf4[q2.y];
            float4 ED = e4[q3.y], RD = rbf4[q3.y];
            float4 XaC = xv4[q2.x * 3 + 0], XbC = xv4[q2.x * 3 + 1];
            float XcC = xv_old[q2.x * 12 + 8];
            float4 XaD = xv4[q3.x * 3 + 0], XbD = xv4[q3.x * 3 + 1];
            float XcD = xv_old[q3.x * 12 + 8];
            // compute both edges
            edge(t0, EA, RA, XaA, XbA, XcA);
            edge(t1, EB, RB, XaB, XbB, XcB);
            // rotate by 2
            q0 = q2; q1 = q3; q2 = q4; q3 = q5; q4 = q6; q5 = q7;
            t0 = t2; t1 = t3; t2 = t4; t3 = t5;
            EA = EC; EB = ED; RA = RC; RB = RD;
            XaA = XaC; XbA = XbC; XcA = XcC;
            XaB = XaD; XbB = XbD; XcB = XcD;
        }
        if (i < deg)  // odd tail: stream A holds edge deg-1
            edge(t0, EA, RA, XaA, XbA, XcA);
    }
    // unpack packed accumulators
    float T[4][12];
    float TbF[12];
#pragma unroll
    for (int c = 0; c < 4; c++)
#pragma unroll
        for (int p = 0; p < 6; p++) {
            T[c][2 * p] = T2[c][p].x;
            T[c][2 * p + 1] = T2[c][p].y;
        }
#pragma unroll
    for (int p = 0; p < 6; p++) {
        TbF[2 * p] = Tb2[p].x;
        TbF[2 * p + 1] = Tb2[p].y;
    }
    // s_accum write: 4 channels hi/lo
    {
        ushort4 hi, lo;
        hi.x = f2bf(ss[0]); lo.x = f2bf(ss[0] - bf2f(hi.x));
        hi.y = f2bf(ss[1]); lo.y = f2bf(ss[1] - bf2f(hi.y));
        hi.z = f2bf(ss[2]); lo.z = f2bf(ss[2] - bf2f(hi.z));
        hi.w = f2bf(ss[3]); lo.w = f2bf(ss[3] - bf2f(hi.w));
        *(ushort4*)(sah + (size_t)n * 256 + chb) = hi;
        *(ushort4*)(sal + (size_t)n * 256 + chb) = lo;
    }
    // gates: vp[d*3+o] = sum over this lane's 4 channels of wg.T
    float vp[9] = {};
#pragma unroll
    for (int c = 0; c < 4; c++) {
        float4 wA = *(const float4*)(Wg + (size_t)(chb + c) * 12);
        float4 wB = *(const float4*)(Wg + (size_t)(chb + c) * 12 + 4);
        float4 wC = *(const float4*)(Wg + (size_t)(chb + c) * 12 + 8);
        float wg[12] = {wA.x, wA.y, wA.z, wA.w, wB.x, wB.y, wB.z, wB.w,
                        wC.x, wC.y, wC.z, wC.w};
#pragma unroll
        for (int d = 0; d < 3; d++)
#pragma unroll
            for (int o = 0; o < 3; o++) {
                float v = vp[d * 3 + o];
                v = fmaf(wg[o * 4 + 0], T[c][d * 4 + 0], v);
                v = fmaf(wg[o * 4 + 1], T[c][d * 4 + 1], v);
                v = fmaf(wg[o * 4 + 2], T[c][d * 4 + 2], v);
                v = fmaf(wg[o * 4 + 3], T[c][d * 4 + 3], v);
                vp[d * 3 + o] = v;
            }
    }
#pragma unroll
    for (int j = 0; j < 9; j++) {
        float v = vp[j];
        v += __shfl_down(v, 32);
        v += __shfl_down(v, 16);
        v += __shfl_down(v, 8);
        v += __shfl_down(v, 4);
        v += __shfl_down(v, 2);
        v += __shfl_down(v, 1);
        vp[j] = v;
    }
    if (lane == 0) {
        if (!addResid) {  // layer 0: publish x_e = segsum(e_v, tgt)
            x_e[n * 3 + 0] = TbF[3];
            x_e[n * 3 + 1] = TbF[7];
            x_e[n * 3 + 2] = TbF[11];
        }
#pragma unroll
        for (int d = 0; d < 3; d++)
#pragma unroll
            for (int o = 0; o < 3; o++) {
                float v = vp[d * 3 + o];
                v = fmaf(bg[o * 4 + 0], TbF[d * 4 + 0], v);
                v = fmaf(bg[o * 4 + 1], TbF[d * 4 + 1], v);
                v = fmaf(bg[o * 4 + 2], TbF[d * 4 + 2], v);
                v = fmaf(bg[o * 4 + 3], TbF[d * 4 + 3], v);
                if (addResid) v += xv_old[n * 12 + d * 3 + o];
                xv_new[n * 12 + d * 3 + o] = v;
            }
    }
}

// ---------------------------------------------------------------------------
// Pooling stage 1: 8 slices per graph (1024 blocks), partial sums, no atomics.
__global__ __launch_bounds__(256) void k_pool8(
    const int* __restrict__ grange, const int* __restrict__ xids,
    const ushort* __restrict__ xsh, const ushort* __restrict__ xsl,
    const float* __restrict__ xv, const float* __restrict__ x_e,
    const float* __restrict__ graph_emb,
    float* __restrict__ partS, float* __restrict__ partA) {
    int b = blockIdx.x, s = blockIdx.y, ch = threadIdx.x;
    int lo = grange[b], hi = grange[b + 1];
    float ps = 0.0f;
    for (int n = lo + s; n < hi; n += 8)
        ps += bf2f(xsh[n * 256 + ch]) + bf2f(xsl[n * 256 + ch]);
    partS[(b * 8 + s) * 256 + ch] = ps;
    if (ch < 15) {
        float v = 0.0f;
        if (ch < 9) {
            for (int n = lo + s; n < hi; n += 8) v += xv[n * 12 + ch];
        } else if (ch < 12) {
            int k = ch - 9;
            for (int n = lo + s; n < hi; n += 8) v += graph_emb[xids[n] * 3 + k];
        } else {
            int k = ch - 12;
            for (int n = lo + s; n < hi; n += 8) v += x_e[n * 3 + k];
        }
        partA[(b * 8 + s) * 16 + ch] = v;
    }
}

// ---------------------------------------------------------------------------
// Pooling stage 2 + output heads. One block per graph.
__global__ __launch_bounds__(256) void k_heads(
    const int* __restrict__ grange, const float* __restrict__ partS,
    const float* __restrict__ partA, const float* __restrict__ W_v,
    const float* __restrict__ W_s, const float* __restrict__ b_s,
    float* __restrict__ out) {
    int b = blockIdx.x, ch = threadIdx.x;
    int lane = ch & 63, wid = ch >> 6;
    float cinv = 1.0f / fmaxf((float)(grange[b + 1] - grange[b]), 1.0f);
    float ps = 0.0f;
#pragma unroll
    for (int s = 0; s < 8; s++) ps += partS[(b * 8 + s) * 256 + ch];
    ps *= cinv;
    float c0 = ps * W_s[ch * 3 + 0];
    float c1 = ps * W_s[ch * 3 + 1];
    float c2 = ps * W_s[ch * 3 + 2];
#pragma unroll
    for (int s = 32; s > 0; s >>= 1) {
        c0 += __shfl_down(c0, s);
        c1 += __shfl_down(c1, s);
        c2 += __shfl_down(c2, s);
    }
    __shared__ float sred[4][3];
    __shared__ float aux[15];  // [0..8]=pooled_v, [9..11]=u_s, [12..14]=u_v
    if (lane == 0) { sred[wid][0] = c0; sred[wid][1] = c1; sred[wid][2] = c2; }
    if (ch < 15) {
        float v = 0.0f;
#pragma unroll
        for (int s = 0; s < 8; s++) v += partA[(b * 8 + s) * 16 + ch];
        aux[ch] = v * cinv;
    }
    __syncthreads();
    if (ch == 0) {
        float os[3];
#pragma unroll
        for (int o = 0; o < 3; o++) {
            float v = sred[0][o] + sred[1][o] + sred[2][o] + sred[3][o] + b_s[o];
#pragma unroll
            for (int k = 0; k < 3; k++) v = fmaf(aux[9 + k], W_s[(256 + k) * 3 + o], v);
            os[o] = v;
        }
#pragma unroll
        for (int d = 0; d < 3; d++) {
#pragma unroll
            for (int o = 0; o < 3; o++) {
                float v = aux[12 + d] * W_v[3 * 3 + o];
#pragma unroll
                for (int c = 0; c < 3; c++) v = fmaf(aux[d * 3 + c], W_v[c * 3 + o], v);
                out[b * 12 + d * 4 + o] = v;
            }
            out[b * 12 + d * 4 + 3] = os[d];
        }
    }
}

// ---------------------------------------------------------------------------
extern "C" void kernel_launch(void* const* d_in, const int* in_sizes, int n_in, void* d_out,
                              int out_size, void* d_ws, size_t ws_size, hipStream_t stream) {
    const int* x = (const int*)d_in[0];
    const int* ai = (const int*)d_in[1];
    const float* e = (const float*)d_in[2];
    const int* gid = (const int*)d_in[3];
    const float* element_emb = (const float*)d_in[5];
    const float* graph_emb = (const float*)d_in[6];
    const float* W_e = (const float*)d_in[7];
    const float* b_e = (const float*)d_in[8];
    const float *Wm[4], *bmv[4], *Wg[4], *bg[4], *Wu[4], *bu[4];
    for (int j = 0; j < 4; j++) {
        Wm[j] = (const float*)d_in[9 + 6 * j];
        bmv[j] = (const float*)d_in[10 + 6 * j];
        Wg[j] = (const float*)d_in[11 + 6 * j];
        bg[j] = (const float*)d_in[12 + 6 * j];
        Wu[j] = (const float*)d_in[13 + 6 * j];
        bu[j] = (const float*)d_in[14 + 6 * j];
    }
    const float* W_v = (const float*)d_in[33];
    const float* W_s = (const float*)d_in[34];
    const float* b_s = (const float*)d_in[35];
    float* out = (float*)d_out;

    char* ws = (char*)d_ws;
    size_t o = 0;
    auto alloc = [&](size_t bytes) -> char* {
        char* p = ws + o;
        o += (bytes + 255) / 256 * 256;
        return p;
    };
    // --- zeroed block (must stay first & contiguous) ---
    int* deg = (int*)alloc(NN * 4);
    int* dcur = (int*)alloc(256 * 4);
    size_t zeroBytes = o;
    // --- rest ---
    int* off_a = (int*)alloc((NN + 1) * 4);
    int* grange = (int*)alloc((NB + 1) * 4);
    int* dofs = (int*)alloc(256 * 4);
    int* perm = (int*)alloc(NN * 4);
    int* rankA = (int*)alloc((size_t)NE * 4);
    int2* se = (int2*)alloc((size_t)(NE + 64) * 8);  // +64 zeroed pad for prefetch
    float4* rbf4 = (float4*)alloc((size_t)NE * 16);
    float* x_e = (float*)alloc(NN * 3 * 4);
    ushort* t_bf = (ushort*)alloc((size_t)NNP * 256 * 2);
    ushort* xsh = (ushort*)alloc((size_t)NNP * 256 * 2);
    ushort* xsl = (ushort*)alloc((size_t)NNP * 256 * 2);
    ushort* sah = (ushort*)alloc((size_t)NNP * 256 * 2);
    ushort* sal = (ushort*)alloc((size_t)NNP * 256 * 2);
    float* xvA = (float*)alloc((size_t)NN * 12 * 4);
    float* xvB = (float*)alloc((size_t)NN * 12 * 4);
    float* Wcomb = (float*)alloc(4 * 3 * 256 * 4);
    float* ccb = (float*)alloc(4 * 256 * 4);
    ushort* WT = (ushort*)alloc((size_t)8 * 131072 * 2);  // 8 mats x (hi+lo) planes
    ushort* ttab = (ushort*)alloc((size_t)84 * 256 * 2);
    float* partS = (float*)alloc((size_t)NB * 8 * 256 * 4);
    float* partA = (float*)alloc((size_t)NB * 8 * 16 * 4);

    hipMemsetAsync(d_ws, 0, zeroBytes, stream);

    dim3 eb((NE + 255) / 256);
    dim3 nb((NN + 255) / 256);
    k_edge_prep<<<eb, 256, 0, stream>>>(ai, e, deg, rankA, rbf4);
    k_wprep_all<<<228, 256, 0, stream>>>(element_emb, W_e, b_e, Wm[0], Wm[1], Wm[2], Wm[3],
                                         bmv[0], bmv[1], bmv[2], bmv[3], Wu[0], Wu[1], Wu[2],
                                         Wu[3], ttab, Wcomb, ccb, WT);
    k_node_prep<<<NN, 256, 0, stream>>>(x, element_emb, ttab, xsh, xsl, xvA, t_bf);
    k_scan<<<1, 1024, 0, stream>>>(deg, gid, off_a, dofs, grange);
    k_permute<<<nb, 256, 0, stream>>>(deg, dofs, dcur, perm);
    k_scatter<<<eb, 256, 0, stream>>>(ai, rankA, off_a, se);

    float* xv_cur = xvA;
    float* xv_nxt = xvB;
    dim3 ggrid(NNP / 128, 2);
    for (int j = 0; j < 4; j++) {
        const ushort* WmT = WT + (size_t)(2 * j) * 131072;
        const ushort* WuT = WT + (size_t)(2 * j + 1) * 131072;
        // t = xs @ Wm_top: 1-pass (AhBh), bf16 output. Layer 0: t from ttab.
        if (j > 0)
            k_gemm_bf16<<<ggrid, 256, 0, stream>>>(xsh, nullptr, WmT, nullptr, nullptr,
                                                   nullptr, nullptr, t_bf, nullptr);
        k_edge<<<NN / 4, 256, 0, stream>>>(perm, se, off_a, t_bf, xv_cur, (const float4*)e,
                                           rbf4, Wcomb + j * 768, ccb + j * 256, Wg[j], bg[j],
                                           sah, sal, x_e, xv_nxt, j > 0 ? 1 : 0);
        // xs = relu(s_accum @ Wu + bu) (+resid): 2-pass (AhBh+AlBh), hi/lo out
        k_gemm_bf16<<<ggrid, 256, 0, stream>>>(sah, sal, WuT, nullptr, bu[j],
                                               (j > 0) ? xsh : nullptr, (j > 0) ? xsl : nullptr,
                                               xsh, xsl);
        float* tmp = xv_cur;
        xv_cur = xv_nxt;
        xv_nxt = tmp;
    }
    k_pool8<<<dim3(NB, 8), 256, 0, stream>>>(grange, x, xsh, xsl, xv_cur, x_e, graph_emb,
                                             partS, partA);
    k_heads<<<NB, 256, 0, stream>>>(grange, partS, partA, W_v, W_s, b_s, out);
}

// Round 16
// 773.503 us; speedup vs baseline: 1.0818x; 1.0818x over previous
//
#include <hip/hip_runtime.h>

#define NN 20000      // nodes
#define NNP 20096     // nodes padded to 128 (GEMM tiles, no M-checks)
#define NE 320000     // edges
#define NB 128        // graphs
// EMB = 256 fixed throughout

typedef __attribute__((ext_vector_type(8))) short short8;
typedef __attribute__((ext_vector_type(4))) float floatx4;
typedef __attribute__((ext_vector_type(2))) float floatv2;

__device__ __forceinline__ void atomAddF(float* p, float v) { unsafeAtomicAdd(p, v); }

__device__ __forceinline__ ushort f2bf(float x) {
    union { float f; unsigned u; } v; v.f = x;
    unsigned r = v.u + 0x7FFFu + ((v.u >> 16) & 1u);
    return (ushort)(r >> 16);
}
__device__ __forceinline__ float bf2f(ushort h) {
    union { float f; unsigned u; } v; v.u = ((unsigned)h) << 16;
    return v.f;
}

// ---------------------------------------------------------------------------
// Edge prep: degree histogram; rank[idx]; rbf4[idx] = {r0,r1,r2,0} (edge-indexed,
// coalesced). RBF truncated to 3 components (r3..r9 <= ~8e-13).
__global__ void k_edge_prep(const int* __restrict__ ai, const float* __restrict__ e,
                            int* __restrict__ deg, int* __restrict__ rankA,
                            float4* __restrict__ rbf4) {
    int idx = blockIdx.x * 256 + threadIdx.x;
    if (idx >= NE) return;
    rankA[idx] = atomicAdd(&deg[ai[2 * idx + 1]], 1);
    float w = e[idx * 4 + 3];
    float d0 = w;
    float d1 = w - (8.0f / 9.0f);
    float d2 = w - (16.0f / 9.0f);
    rbf4[idx] = make_float4(__expf(-10.0f * d0 * d0), __expf(-10.0f * d1 * d1),
                            __expf(-10.0f * d2 * d2), 0.0f);
}

// ---------------------------------------------------------------------------
// Node prep: x_s (bf16 hi/lo) = element_emb[x], x_v = ones, t0 = ttab[x]
__global__ void k_node_prep(const int* __restrict__ x, const float* __restrict__ element_emb,
                            const ushort* __restrict__ ttab, ushort* __restrict__ xsh,
                            ushort* __restrict__ xsl, float* __restrict__ xv_init,
                            ushort* __restrict__ t_bf) {
    int n = blockIdx.x, tid = threadIdx.x;
    int xe = x[n];
    float v = element_emb[xe * 256 + tid];
    ushort h = f2bf(v);
    xsh[n * 256 + tid] = h;
    xsl[n * 256 + tid] = f2bf(v - bf2f(h));
    t_bf[n * 256 + tid] = ttab[xe * 256 + tid];
    if (tid < 12) xv_init[n * 12 + tid] = 1.0f;
}

// ---------------------------------------------------------------------------
// Exclusive prefix sum of deg -> off, graph ranges, AND degree-sorted node
// permutation (counting sort entirely in-block via LDS cursors — R16: folds
// the old k_permute dispatch; avoids R12's hot global-atomic mistake).
__global__ void k_scan(const int* __restrict__ deg, const int* __restrict__ gid,
                       int* __restrict__ off, int* __restrict__ grange,
                       int* __restrict__ perm) {
    __shared__ int ps[1024];
    __shared__ int dh[256];
    __shared__ int ddofs[256];
    int tid = threadIdx.x;
    if (tid < 256) dh[tid] = 0;
    __syncthreads();
    int base = tid * 20;  // 1024*20 = 20480 >= NN
    int dl[20];
    int sum = 0;
#pragma unroll
    for (int i = 0; i < 20; i++) {
        int idx = base + i;
        dl[i] = (idx < NN) ? deg[idx] : 0;
        sum += dl[i];
    }
    ps[tid] = sum;
#pragma unroll
    for (int i = 0; i < 20; i++) {
        int idx = base + i;
        if (idx < NN) atomicAdd(&dh[min(dl[i], 255)], 1);
    }
    __syncthreads();
#pragma unroll
    for (int d = 1; d < 1024; d <<= 1) {
        int t = (tid >= d) ? ps[tid - d] : 0;
        __syncthreads();
        ps[tid] += t;
        __syncthreads();
    }
    int run = (tid > 0) ? ps[tid - 1] : 0;
#pragma unroll
    for (int i = 0; i < 20; i++) {
        int idx = base + i;
        if (idx < NN) {
            off[idx] = run;
            run += dl[i];
        }
    }
    if (tid == 1023) off[NN] = run;
    if (tid < 256) {
        int s = 0;
        for (int dd = tid + 1; dd < 256; dd++) s += dh[dd];
        ddofs[tid] = s;
        dh[tid] = 0;  // reuse as cursor
    }
    // graph ranges (independent of scan results)
#pragma unroll
    for (int i = 0; i < 20; i++) {
        int idx = base + i;
        if (idx < NN) {
            int g = gid[idx];
            int gp = (idx == 0) ? -1 : gid[idx - 1];
            for (int bb = gp + 1; bb <= g; bb++) grange[bb] = idx;
            if (idx == NN - 1)
                for (int bb = g + 1; bb <= NB; bb++) grange[bb] = NN;
        }
    }
    __syncthreads();
    // degree-descending permutation via LDS cursors
#pragma unroll
    for (int i = 0; i < 20; i++) {
        int idx = base + i;
        if (idx < NN) {
            int d = min(dl[i], 255);
            int pos = ddofs[d] + atomicAdd(&dh[d], 1);
            perm[pos] = idx;
        }
    }
}

// ---------------------------------------------------------------------------
// Scatter into CSR slots — NO atomics (rank precomputed), 8B per edge.
__global__ void k_scatter(const int* __restrict__ ai, const int* __restrict__ rankA,
                          const int* __restrict__ off, int2* __restrict__ se) {
    int idx = blockIdx.x * 256 + threadIdx.x;
    if (idx < 64) se[NE + idx] = make_int2(0, 0);  // zero pad for prefetch
    if (idx >= NE) return;
    int src = ai[2 * idx + 0], tgt = ai[2 * idx + 1];
    int p = off[tgt] + rankA[idx];
    se[p] = make_int2(src, idx);
}

// ---------------------------------------------------------------------------
// Merged weight prep (one dispatch, 228 blocks):
//  b in [0,84)    : ttab[el] = element_emb[el] @ Wm0_top -> bf16
//  b in [84,100)  : Wcomb/cc (idx = b-84: k = idx&3, j = idx>>2)
//  b in [100,228) : weight transpose + hi/lo split
__global__ void k_wprep_all(const float* __restrict__ element_emb,
                            const float* __restrict__ W_e, const float* __restrict__ b_e,
                            const float* __restrict__ Wm0, const float* __restrict__ Wm1,
                            const float* __restrict__ Wm2, const float* __restrict__ Wm3,
                            const float* __restrict__ bm0, const float* __restrict__ bm1,
                            const float* __restrict__ bm2, const float* __restrict__ bm3,
                            const float* __restrict__ Wu0, const float* __restrict__ Wu1,
                            const float* __restrict__ Wu2, const float* __restrict__ Wu3,
                            ushort* __restrict__ ttab, float* __restrict__ Wcomb,
                            float* __restrict__ cc, ushort* __restrict__ WT) {
    int b = blockIdx.x;
    int ch = threadIdx.x;
    if (b < 84) {
        float s = 0.0f;
        for (int r = 0; r < 256; r++)
            s = fmaf(element_emb[b * 256 + r], Wm0[r * 256 + ch], s);
        ttab[b * 256 + ch] = f2bf(s);
        return;
    }
    if (b < 100) {
        int idx = b - 84;
        int k = idx & 3, j = idx >> 2;
        const float* Wm = (j == 0) ? Wm0 : (j == 1) ? Wm1 : (j == 2) ? Wm2 : Wm3;
        const float* bm = (j == 0) ? bm0 : (j == 1) ? bm1 : (j == 2) ? bm2 : bm3;
        if (k < 3) {
            float s = 0.0f;
            for (int r = 0; r < 256; r++)
                s = fmaf(W_e[k * 256 + r], Wm[(256 + r) * 256 + ch], s);
            Wcomb[j * 768 + k * 256 + ch] = s;
        } else {
            float s = bm[ch];
            for (int r = 0; r < 256; r++)
                s = fmaf(b_e[r], Wm[(256 + r) * 256 + ch], s);
            cc[j * 256 + ch] = s;
        }
        return;
    }
    // transpose + split
    int idx = b - 100;
    int ktb = idx & 3, ntb = (idx >> 2) & 3, z = idx >> 4;
    const float* Ws[8] = {Wm0, Wu0, Wm1, Wu1, Wm2, Wu2, Wm3, Wu3};
    const float* W = Ws[z];
    ushort* outh = WT + (size_t)z * 131072;
    ushort* outl = outh + 65536;
    __shared__ float tile[64][65];
    int kt = ktb * 64, nt = ntb * 64;
    int c = ch & 63, rq = ch >> 6;
#pragma unroll
    for (int r0 = 0; r0 < 16; r0++) {
        int k = kt + rq * 16 + r0;
        tile[rq * 16 + r0][c] = W[k * 256 + nt + c];
    }
    __syncthreads();
#pragma unroll
    for (int r0 = 0; r0 < 16; r0++) {
        int n = nt + rq * 16 + r0;
        float v = tile[c][rq * 16 + r0];  // = W[kt+c][n]
        ushort h = f2bf(v);
        outh[n * 256 + kt + c] = h;
        outl[n * 256 + kt + c] = f2bf(v - bf2f(h));
    }
}

// ---------------------------------------------------------------------------
// bf16 hi/lo split-precision MFMA GEMM: C[NNP,256] = A[NNP,256] @ W[256,256].
// R9 structure (128x128 tile). Staging via global_load_lds width=16.
// Al==null -> skip AlBh; Bl==null -> skip AhBl.
__global__ __launch_bounds__(256) void k_gemm_bf16(
    const ushort* __restrict__ Ah, const ushort* __restrict__ Al,
    const ushort* __restrict__ Bh, const ushort* __restrict__ Bl,
    const float* __restrict__ bias,
    const ushort* __restrict__ Rh, const ushort* __restrict__ Rl,
    ushort* __restrict__ Coh, ushort* __restrict__ Col) {
    __shared__ __align__(16) ushort As[2][128][32];
    __shared__ __align__(16) ushort Bs[2][128][32];
    const int tid = threadIdx.x;
    const int lane = tid & 63, wid = tid >> 6;
    const int bm0 = blockIdx.x * 128, bn0 = blockIdx.y * 128;
    const int wm0 = (wid & 1) * 64, wn0 = (wid >> 1) * 64;
    const int lm = lane & 15, q8 = (lane >> 4) * 8;
    const int lr = lane >> 2, lp = lane & 3;  // 16-row group: row-in-group, 16B part
    floatx4 acc[4][4] = {};
    for (int k0 = 0; k0 < 256; k0 += 32) {
        __syncthreads();
        // async global->LDS: one instr = 64 lanes x 16B = 16 rows of a plane
#pragma unroll
        for (int q = 0; q < 2; q++) {
            int rw = (wid * 2 + q) * 16;
            int grow = rw + lr;
            size_t ga = (size_t)(bm0 + grow) * 256 + k0 + lp * 8;
            size_t gb = (size_t)(bn0 + grow) * 256 + k0 + lp * 8;
            __builtin_amdgcn_global_load_lds(
                (const __attribute__((address_space(1))) void*)(Ah + ga),
                (__attribute__((address_space(3))) void*)&As[0][rw][0], 16, 0, 0);
            if (Al)
                __builtin_amdgcn_global_load_lds(
                    (const __attribute__((address_space(1))) void*)(Al + ga),
                    (__attribute__((address_space(3))) void*)&As[1][rw][0], 16, 0, 0);
            __builtin_amdgcn_global_load_lds(
                (const __attribute__((address_space(1))) void*)(Bh + gb),
                (__attribute__((address_space(3))) void*)&Bs[0][rw][0], 16, 0, 0);
            if (Bl)
                __builtin_amdgcn_global_load_lds(
                    (const __attribute__((address_space(1))) void*)(Bl + gb),
                    (__attribute__((address_space(3))) void*)&Bs[1][rw][0], 16, 0, 0);
        }
        __syncthreads();
        short8 ah[4], al[4], bh[4], bl[4];
#pragma unroll
        for (int mt = 0; mt < 4; mt++) {
            ah[mt] = *(const short8*)&As[0][wm0 + mt * 16 + lm][q8];
            if (Al) al[mt] = *(const short8*)&As[1][wm0 + mt * 16 + lm][q8];
        }
#pragma unroll
        for (int nt = 0; nt < 4; nt++) {
            bh[nt] = *(const short8*)&Bs[0][wn0 + nt * 16 + lm][q8];
            if (Bl) bl[nt] = *(const short8*)&Bs[1][wn0 + nt * 16 + lm][q8];
        }
#pragma unroll
        for (int mt = 0; mt < 4; mt++)
#pragma unroll
            for (int nt = 0; nt < 4; nt++) {
                acc[mt][nt] = __builtin_amdgcn_mfma_f32_16x16x32_bf16(ah[mt], bh[nt], acc[mt][nt], 0, 0, 0);
                if (Al)
                    acc[mt][nt] = __builtin_amdgcn_mfma_f32_16x16x32_bf16(al[mt], bh[nt], acc[mt][nt], 0, 0, 0);
                if (Bl)
                    acc[mt][nt] = __builtin_amdgcn_mfma_f32_16x16x32_bf16(ah[mt], bl[nt], acc[mt][nt], 0, 0, 0);
            }
    }
    const int rq4 = (lane >> 4) * 4;
#pragma unroll
    for (int mt = 0; mt < 4; mt++) {
        int rbase = bm0 + wm0 + mt * 16 + rq4;
#pragma unroll
        for (int nt = 0; nt < 4; nt++) {
            int col = bn0 + wn0 + nt * 16 + lm;
#pragma unroll
            for (int r = 0; r < 4; r++) {
                int row = rbase + r;
                float v = acc[mt][nt][r];
                if (!Col) {
                    Coh[row * 256 + col] = f2bf(v);
                } else {
                    v += bias[col];
                    v = fmaxf(v, 0.0f);
                    if (Rh) v += bf2f(Rh[row * 256 + col]) + bf2f(Rl[row * 256 + col]);
                    ushort h = f2bf(v);
                    Coh[row * 256 + col] = h;
                    Col[row * 256 + col] = f2bf(v - bf2f(h));
                }
            }
        }
    }
}

// ---------------------------------------------------------------------------
// Fused edge kernel: one wave per node (degree-sorted via perm), 4 ch/lane,
// unrolled x2, packed-fp32 T accumulation. R16: s_accum written as a SINGLE
// bf16 plane (2^-9 relative, same order as the t-path quantization).
__global__ __launch_bounds__(256) void k_edge(const int* __restrict__ perm,
                                              const int2* __restrict__ seP,
                                              const int* __restrict__ off,
                                              const ushort* __restrict__ tbf,
                                              const float* __restrict__ xv_old,
                                              const float4* __restrict__ e4,
                                              const float4* __restrict__ rbf4,
                                              const float* __restrict__ Wcomb,
                                              const float* __restrict__ cc,
                                              const float* __restrict__ Wg,
                                              const float* __restrict__ bg,
                                              ushort* __restrict__ sa,
                                              float* __restrict__ x_e,
                                              float* __restrict__ xv_new, int addResid) {
    const int lane = threadIdx.x & 63, wid = threadIdx.x >> 6;
    const int n = perm[blockIdx.x * 4 + wid];
    const int chb = lane * 4;  // this lane's 4 channels
    const int start = off[n];
    const int deg = off[n + 1] - start;
    float wcs0[4], wcs1[4], wcs2[4], ccs[4];
    {
        float4 a = *(const float4*)(Wcomb + chb);
        float4 b = *(const float4*)(Wcomb + 256 + chb);
        float4 c = *(const float4*)(Wcomb + 512 + chb);
        float4 d = *(const float4*)(cc + chb);
        wcs0[0] = a.x; wcs0[1] = a.y; wcs0[2] = a.z; wcs0[3] = a.w;
        wcs1[0] = b.x; wcs1[1] = b.y; wcs1[2] = b.z; wcs1[3] = b.w;
        wcs2[0] = c.x; wcs2[1] = c.y; wcs2[2] = c.z; wcs2[3] = c.w;
        ccs[0] = d.x; ccs[1] = d.y; ccs[2] = d.z; ccs[3] = d.w;
    }
    floatv2 T2[4][6] = {};
    floatv2 Tb2[6] = {};
    float ss[4] = {};
    const float4* xv4 = (const float4*)xv_old;

    auto edge = [&](ushort4 t, float4 E, float4 R, float4 Xa, float4 Xb, float Xc) {
        floatv2 B2[6];
        B2[0] = floatv2{Xa.x, Xa.y};
        B2[1] = floatv2{Xa.z, E.x};
        B2[2] = floatv2{Xa.w, Xb.x};
        B2[3] = floatv2{Xb.y, E.y};
        B2[4] = floatv2{Xb.z, Xb.w};
        B2[5] = floatv2{Xc, E.z};
        float tf[4] = {bf2f(t.x), bf2f(t.y), bf2f(t.z), bf2f(t.w)};
#pragma unroll
        for (int c = 0; c < 4; c++) {
            float m = tf[c] + ccs[c];
            m = fmaf(R.x, wcs0[c], m);
            m = fmaf(R.y, wcs1[c], m);
            m = fmaf(R.z, wcs2[c], m);
            m = fmaxf(m, 0.0f);
            ss[c] += m;
            floatv2 mm = floatv2{m, m};
#pragma unroll
            for (int p = 0; p < 6; p++)
                asm("v_pk_fma_f32 %0, %1, %2, %0" : "+v"(T2[c][p]) : "v"(B2[p]), "v"(mm));
        }
#pragma unroll
        for (int p = 0; p < 6; p++)
            asm("v_pk_add_f32 %0, %1, %0" : "+v"(Tb2[p]) : "v"(B2[p]));
    };

    if (deg > 0) {
        int2 q0 = seP[start + 0], q1 = seP[start + 1], q2 = seP[start + 2],
             q3 = seP[start + 3], q4 = seP[start + 4], q5 = seP[start + 5];
        ushort4 t0 = *(const ushort4*)(tbf + (size_t)q0.x * 256 + chb);
        ushort4 t1 = *(const ushort4*)(tbf + (size_t)q1.x * 256 + chb);
        ushort4 t2 = *(const ushort4*)(tbf + (size_t)q2.x * 256 + chb);
        ushort4 t3 = *(const ushort4*)(tbf + (size_t)q3.x * 256 + chb);
        float4 EA = e4[q0.y], RA = rbf4[q0.y];
        float4 EB = e4[q1.y], RB = rbf4[q1.y];
        float4 XaA = xv4[q0.x * 3 + 0], XbA = xv4[q0.x * 3 + 1];
        float XcA = xv_old[q0.x * 12 + 8];
        float4 XaB = xv4[q1.x * 3 + 0], XbB = xv4[q1.x * 3 + 1];
        float XcB = xv_old[q1.x * 12 + 8];
        int i = 0;
        for (; i + 1 < deg; i += 2) {
            // prefetch (all chain-free: induction addresses or >=2-iter-old regs)
            int2 q6 = seP[start + i + 6];
            int2 q7 = seP[start + i + 7];
            ushort4 t4 = *(const ushort4*)(tbf + (size_t)q4.x * 256 + chb);
            ushort4 t5 = *(const ushort4*)(tbf + (size_t)q5.x * 256 + chb);
            float4 EC = e4[q2.y], RC = rbf4[q2.y];
            float4 ED = e4[q3.y], RD = rbf4[q3.y];
            float4 XaC = xv4[q2.x * 3 + 0], XbC = xv4[q2.x * 3 + 1];
            float XcC = xv_old[q2.x * 12 + 8];
            float4 XaD = xv4[q3.x * 3 + 0], XbD = xv4[q3.x * 3 + 1];
            float XcD = xv_old[q3.x * 12 + 8];
            // compute both edges
            edge(t0, EA, RA, XaA, XbA, XcA);
            edge(t1, EB, RB, XaB, XbB, XcB);
            // rotate by 2
            q0 = q2; q1 = q3; q2 = q4; q3 = q5; q4 = q6; q5 = q7;
            t0 = t2; t1 = t3; t2 = t4; t3 = t5;
            EA = EC; EB = ED; RA = RC; RB = RD;
            XaA = XaC; XbA = XbC; XcA = XcC;
            XaB = XaD; XbB = XbD; XcB = XcD;
        }
        if (i < deg)  // odd tail: stream A holds edge deg-1
            edge(t0, EA, RA, XaA, XbA, XcA);
    }
    // unpack packed accumulators
    float T[4][12];
    float TbF[12];
#pragma unroll
    for (int c = 0; c < 4; c++)
#pragma unroll
        for (int p = 0; p < 6; p++) {
            T[c][2 * p] = T2[c][p].x;
            T[c][2 * p + 1] = T2[c][p].y;
        }
#pragma unroll
    for (int p = 0; p < 6; p++) {
        TbF[2 * p] = Tb2[p].x;
        TbF[2 * p + 1] = Tb2[p].y;
    }
    // s_accum write: 4 channels, single bf16 plane
    {
        ushort4 hi;
        hi.x = f2bf(ss[0]);
        hi.y = f2bf(ss[1]);
        hi.z = f2bf(ss[2]);
        hi.w = f2bf(ss[3]);
        *(ushort4*)(sa + (size_t)n * 256 + chb) = hi;
    }
    // gates: vp[d*3+o] = sum over this lane's 4 channels of wg.T
    float vp[9] = {};
#pragma unroll
    for (int c = 0; c < 4; c++) {
        float4 wA = *(const float4*)(Wg + (size_t)(chb + c) * 12);
        float4 wB = *(const float4*)(Wg + (size_t)(chb + c) * 12 + 4);
        float4 wC = *(const float4*)(Wg + (size_t)(chb + c) * 12 + 8);
        float wg[12] = {wA.x, wA.y, wA.z, wA.w, wB.x, wB.y, wB.z, wB.w,
                        wC.x, wC.y, wC.z, wC.w};
#pragma unroll
        for (int d = 0; d < 3; d++)
#pragma unroll
            for (int o = 0; o < 3; o++) {
                float v = vp[d * 3 + o];
                v = fmaf(wg[o * 4 + 0], T[c][d * 4 + 0], v);
                v = fmaf(wg[o * 4 + 1], T[c][d * 4 + 1], v);
                v = fmaf(wg[o * 4 + 2], T[c][d * 4 + 2], v);
                v = fmaf(wg[o * 4 + 3], T[c][d * 4 + 3], v);
                vp[d * 3 + o] = v;
            }
    }
#pragma unroll
    for (int j = 0; j < 9; j++) {
        float v = vp[j];
        v += __shfl_down(v, 32);
        v += __shfl_down(v, 16);
        v += __shfl_down(v, 8);
        v += __shfl_down(v, 4);
        v += __shfl_down(v, 2);
        v += __shfl_down(v, 1);
        vp[j] = v;
    }
    if (lane == 0) {
        if (!addResid) {  // layer 0: publish x_e = segsum(e_v, tgt)
            x_e[n * 3 + 0] = TbF[3];
            x_e[n * 3 + 1] = TbF[7];
            x_e[n * 3 + 2] = TbF[11];
        }
#pragma unroll
        for (int d = 0; d < 3; d++)
#pragma unroll
            for (int o = 0; o < 3; o++) {
                float v = vp[d * 3 + o];
                v = fmaf(bg[o * 4 + 0], TbF[d * 4 + 0], v);
                v = fmaf(bg[o * 4 + 1], TbF[d * 4 + 1], v);
                v = fmaf(bg[o * 4 + 2], TbF[d * 4 + 2], v);
                v = fmaf(bg[o * 4 + 3], TbF[d * 4 + 3], v);
                if (addResid) v += xv_old[n * 12 + d * 3 + o];
                xv_new[n * 12 + d * 3 + o] = v;
            }
    }
}

// ---------------------------------------------------------------------------
// Pooling stage 1: 8 slices per graph (1024 blocks), partial sums, no atomics.
__global__ __launch_bounds__(256) void k_pool8(
    const int* __restrict__ grange, const int* __restrict__ xids,
    const ushort* __restrict__ xsh, const ushort* __restrict__ xsl,
    const float* __restrict__ xv, const float* __restrict__ x_e,
    const float* __restrict__ graph_emb,
    float* __restrict__ partS, float* __restrict__ partA) {
    int b = blockIdx.x, s = blockIdx.y, ch = threadIdx.x;
    int lo = grange[b], hi = grange[b + 1];
    float ps = 0.0f;
    for (int n = lo + s; n < hi; n += 8)
        ps += bf2f(xsh[n * 256 + ch]) + bf2f(xsl[n * 256 + ch]);
    partS[(b * 8 + s) * 256 + ch] = ps;
    if (ch < 15) {
        float v = 0.0f;
        if (ch < 9) {
            for (int n = lo + s; n < hi; n += 8) v += xv[n * 12 + ch];
        } else if (ch < 12) {
            int k = ch - 9;
            for (int n = lo + s; n < hi; n += 8) v += graph_emb[xids[n] * 3 + k];
        } else {
            int k = ch - 12;
            for (int n = lo + s; n < hi; n += 8) v += x_e[n * 3 + k];
        }
        partA[(b * 8 + s) * 16 + ch] = v;
    }
}

// ---------------------------------------------------------------------------
// Pooling stage 2 + output heads. One block per graph.
__global__ __launch_bounds__(256) void k_heads(
    const int* __restrict__ grange, const float* __restrict__ partS,
    const float* __restrict__ partA, const float* __restrict__ W_v,
    const float* __restrict__ W_s, const float* __restrict__ b_s,
    float* __restrict__ out) {
    int b = blockIdx.x, ch = threadIdx.x;
    int lane = ch & 63, wid = ch >> 6;
    float cinv = 1.0f / fmaxf((float)(grange[b + 1] - grange[b]), 1.0f);
    float ps = 0.0f;
#pragma unroll
    for (int s = 0; s < 8; s++) ps += partS[(b * 8 + s) * 256 + ch];
    ps *= cinv;
    float c0 = ps * W_s[ch * 3 + 0];
    float c1 = ps * W_s[ch * 3 + 1];
    float c2 = ps * W_s[ch * 3 + 2];
#pragma unroll
    for (int s = 32; s > 0; s >>= 1) {
        c0 += __shfl_down(c0, s);
        c1 += __shfl_down(c1, s);
        c2 += __shfl_down(c2, s);
    }
    __shared__ float sred[4][3];
    __shared__ float aux[15];  // [0..8]=pooled_v, [9..11]=u_s, [12..14]=u_v
    if (lane == 0) { sred[wid][0] = c0; sred[wid][1] = c1; sred[wid][2] = c2; }
    if (ch < 15) {
        float v = 0.0f;
#pragma unroll
        for (int s = 0; s < 8; s++) v += partA[(b * 8 + s) * 16 + ch];
        aux[ch] = v * cinv;
    }
    __syncthreads();
    if (ch == 0) {
        float os[3];
#pragma unroll
        for (int o = 0; o < 3; o++) {
            float v = sred[0][o] + sred[1][o] + sred[2][o] + sred[3][o] + b_s[o];
#pragma unroll
            for (int k = 0; k < 3; k++) v = fmaf(aux[9 + k], W_s[(256 + k) * 3 + o], v);
            os[o] = v;
        }
#pragma unroll
        for (int d = 0; d < 3; d++) {
#pragma unroll
            for (int o = 0; o < 3; o++) {
                float v = aux[12 + d] * W_v[3 * 3 + o];
#pragma unroll
                for (int c = 0; c < 3; c++) v = fmaf(aux[d * 3 + c], W_v[c * 3 + o], v);
                out[b * 12 + d * 4 + o] = v;
            }
            out[b * 12 + d * 4 + 3] = os[d];
        }
    }
}

// ---------------------------------------------------------------------------
extern "C" void kernel_launch(void* const* d_in, const int* in_sizes, int n_in, void* d_out,
                              int out_size, void* d_ws, size_t ws_size, hipStream_t stream) {
    const int* x = (const int*)d_in[0];
    const int* ai = (const int*)d_in[1];
    const float* e = (const float*)d_in[2];
    const int* gid = (const int*)d_in[3];
    const float* element_emb = (const float*)d_in[5];
    const float* graph_emb = (const float*)d_in[6];
    const float* W_e = (const float*)d_in[7];
    const float* b_e = (const float*)d_in[8];
    const float *Wm[4], *bmv[4], *Wg[4], *bg[4], *Wu[4], *bu[4];
    for (int j = 0; j < 4; j++) {
        Wm[j] = (const float*)d_in[9 + 6 * j];
        bmv[j] = (const float*)d_in[10 + 6 * j];
        Wg[j] = (const float*)d_in[11 + 6 * j];
        bg[j] = (const float*)d_in[12 + 6 * j];
        Wu[j] = (const float*)d_in[13 + 6 * j];
        bu[j] = (const float*)d_in[14 + 6 * j];
    }
    const float* W_v = (const float*)d_in[33];
    const float* W_s = (const float*)d_in[34];
    const float* b_s = (const float*)d_in[35];
    float* out = (float*)d_out;

    char* ws = (char*)d_ws;
    size_t o = 0;
    auto alloc = [&](size_t bytes) -> char* {
        char* p = ws + o;
        o += (bytes + 255) / 256 * 256;
        return p;
    };
    // --- zeroed block (must stay first & contiguous) ---
    int* deg = (int*)alloc(NN * 4);
    size_t zeroBytes = o;
    // --- rest ---
    int* off_a = (int*)alloc((NN + 1) * 4);
    int* grange = (int*)alloc((NB + 1) * 4);
    int* perm = (int*)alloc(NN * 4);
    int* rankA = (int*)alloc((size_t)NE * 4);
    int2* se = (int2*)alloc((size_t)(NE + 64) * 8);  // +64 zeroed pad for prefetch
    float4* rbf4 = (float4*)alloc((size_t)NE * 16);
    float* x_e = (float*)alloc(NN * 3 * 4);
    ushort* t_bf = (ushort*)alloc((size_t)NNP * 256 * 2);
    ushort* xsh = (ushort*)alloc((size_t)NNP * 256 * 2);
    ushort* xsl = (ushort*)alloc((size_t)NNP * 256 * 2);
    ushort* sa = (ushort*)alloc((size_t)NNP * 256 * 2);
    float* xvA = (float*)alloc((size_t)NN * 12 * 4);
    float* xvB = (float*)alloc((size_t)NN * 12 * 4);
    float* Wcomb = (float*)alloc(4 * 3 * 256 * 4);
    float* ccb = (float*)alloc(4 * 256 * 4);
    ushort* WT = (ushort*)alloc((size_t)8 * 131072 * 2);  // 8 mats x (hi+lo) planes
    ushort* ttab = (ushort*)alloc((size_t)84 * 256 * 2);
    float* partS = (float*)alloc((size_t)NB * 8 * 256 * 4);
    float* partA = (float*)alloc((size_t)NB * 8 * 16 * 4);

    hipMemsetAsync(d_ws, 0, zeroBytes, stream);

    dim3 eb((NE + 255) / 256);
    k_edge_prep<<<eb, 256, 0, stream>>>(ai, e, deg, rankA, rbf4);
    k_wprep_all<<<228, 256, 0, stream>>>(element_emb, W_e, b_e, Wm[0], Wm[1], Wm[2], Wm[3],
                                         bmv[0], bmv[1], bmv[2], bmv[3], Wu[0], Wu[1], Wu[2],
                                         Wu[3], ttab, Wcomb, ccb, WT);
    k_node_prep<<<NN, 256, 0, stream>>>(x, element_emb, ttab, xsh, xsl, xvA, t_bf);
    k_scan<<<1, 1024, 0, stream>>>(deg, gid, off_a, grange, perm);
    k_scatter<<<eb, 256, 0, stream>>>(ai, rankA, off_a, se);

    float* xv_cur = xvA;
    float* xv_nxt = xvB;
    dim3 ggrid(NNP / 128, 2);
    for (int j = 0; j < 4; j++) {
        const ushort* WmT = WT + (size_t)(2 * j) * 131072;
        const ushort* WuT = WT + (size_t)(2 * j + 1) * 131072;
        // t = xs @ Wm_top: 1-pass (AhBh), bf16 output. Layer 0: t from ttab.
        if (j > 0)
            k_gemm_bf16<<<ggrid, 256, 0, stream>>>(xsh, nullptr, WmT, nullptr, nullptr,
                                                   nullptr, nullptr, t_bf, nullptr);
        k_edge<<<NN / 4, 256, 0, stream>>>(perm, se, off_a, t_bf, xv_cur, (const float4*)e,
                                           rbf4, Wcomb + j * 768, ccb + j * 256, Wg[j], bg[j],
                                           sa, x_e, xv_nxt, j > 0 ? 1 : 0);
        // xs = relu(sa @ Wu + bu) (+resid): 1-pass (AhBh), hi/lo output
        k_gemm_bf16<<<ggrid, 256, 0, stream>>>(sa, nullptr, WuT, nullptr, bu[j],
                                               (j > 0) ? xsh : nullptr, (j > 0) ? xsl : nullptr,
                                               xsh, xsl);
        float* tmp = xv_cur;
        xv_cur = xv_nxt;
        xv_nxt = tmp;
    }
    k_pool8<<<dim3(NB, 8), 256, 0, stream>>>(grange, x, xsh, xsl, xv_cur, x_e, graph_emb,
                                             partS, partA);
    k_heads<<<NB, 256, 0, stream>>>(grange, partS, partA, W_v, W_s, b_s, out);
}